// Round 16
// baseline (208.645 us; speedup 1.0000x reference)
//
#include <hip/hip_runtime.h>

#define B_N 65536
#define M_N 1000000
#define E_N 1310720
#define IN_D 64
#define OUT_D 32
#define BM 128   // rows per block in hproj role
#define XS2 72   // sx row stride in SHORTS (144 B, 16B-aligned rows)
#define NCT 5    // col-tiles: 4 x 16 h-cols + 1 tile holding folded a-dot cols
#define NFRAG (NCT * 2)
#define NBUCK 1024        // (branch<<9) | (row>>7)
#define BCAP 4096         // per-bucket capacity (mean 2560, max ~2800)
#define BK_B 320          // bucket role blocks: 320 x 8192 edges = 2*E_N
#define EPB 8192          // edges per bucket block
#define HP_B ((M_N + BM - 1) / BM)   // 7813 hproj blocks
#define STRIDE 25         // every 25th block is a bucket block

typedef __attribute__((ext_vector_type(8))) short bf16x8;
typedef __attribute__((ext_vector_type(4))) float f32x4;

__device__ __forceinline__ unsigned short f2bf(float f) {
  unsigned u = __float_as_uint(f);
  u += 0x7fffu + ((u >> 16) & 1u);
  return (unsigned short)(u >> 16);
}
__device__ __forceinline__ unsigned pk2(float a, float b) {
  return (unsigned)f2bf(a) | ((unsigned)f2bf(b) << 16);
}
__device__ __forceinline__ float bf2f(unsigned short s) {
  return __uint_as_float(((unsigned)s) << 16);
}

// block 0: zero bucket_cnt; block 1: pack B_ext MFMA fragments.
__global__ __launch_bounds__(256) void k_init(
    int* __restrict__ bucket_cnt,
    const float* __restrict__ Wb, const float* __restrict__ ab,
    const float* __restrict__ Wu, const float* __restrict__ au,
    unsigned* __restrict__ frag_buf)
{
  int t = threadIdx.x;
  if (blockIdx.x == 0) {
    ((int4*)bucket_cnt)[t] = (int4){0, 0, 0, 0};  // 1024 ints = 256 int4
    return;
  }
  for (int p = t; p < NFRAG * 64 * 4; p += 256) {
    int q = p >> 8;
    int rem = p & 255;
    int l = rem >> 2;
    int d = rem & 3;
    int ct = q >> 1, S = q & 1;
    int kb = 32 * S + 8 * (l >> 4);
    int n = 16 * ct + (l & 15);
    float v[2];
    #pragma unroll
    for (int e = 0; e < 2; ++e) {
      int kk = kb + 2 * d + e;
      float val;
      if (n < 32) val = Wb[kk * 32 + n];
      else if (n < 64) val = Wu[kk * 32 + (n - 32)];
      else if (n < 68) {
        const float* W = (n < 66) ? Wb : Wu;
        const float* av = (n < 66) ? ab : au;
        int hi = (n & 1) ? 32 : 0;
        float acc = 0.f;
        for (int j = 0; j < 32; ++j) acc = fmaf(W[kk * 32 + j], av[hi + j], acc);
        val = acc;
      } else val = 0.f;
      v[e] = val;
    }
    frag_buf[p] = pk2(v[0], v[1]);
  }
}

// Fused mid: every 25th block is a bucket block (320 total) with R15's exact
// bucket geometry (8192 edges -> avg 8/bin), re-expressed for 256 threads via
// two-pass edge reads. Remaining 7813 blocks do MFMA hproj. Interleaving
// hides bucket's fabric-atomic stalls under hproj's MFMA/HBM work.
__global__ __launch_bounds__(256) void k_mid(
    const float* __restrict__ emb, const int* __restrict__ uids,
    const unsigned* __restrict__ frag_buf,
    unsigned short* __restrict__ hb, unsigned short* __restrict__ hu,
    float* __restrict__ adb, float* __restrict__ adu,
    float* __restrict__ asb, float* __restrict__ asu,
    const int* __restrict__ prow, const int* __restrict__ pcol,
    const int* __restrict__ nrow, const int* __restrict__ ncol,
    int* __restrict__ bucket_cnt, unsigned* __restrict__ bpack)
{
  __shared__ __align__(16) char smem[BM * XS2 * 2 + 512];  // 18.9 KB union
  int t = threadIdx.x;
  int b = blockIdx.x;
  int q = b / STRIDE;
  bool isb = ((b % STRIDE) == 0) && (q < BK_B);

  if (isb) {
    // ---- bucket role: two-pass, R15 geometry ----
    int* hcnt = (int*)smem;            // [1024]
    int* hbase = hcnt + NBUCK;         // [1024]
    int* rnk = hbase + NBUCK;          // [1024]
    #pragma unroll
    for (int k = 0; k < 4; ++k) {
      hcnt[k * 256 + t] = 0;
      rnk[k * 256 + t] = 0;
    }
    __syncthreads();

    int s_id = q;
    int br = (s_id >= 160) ? 1 : 0;
    const int* rows = br ? nrow : prow;
    const int* cols = br ? ncol : pcol;
    int ebase = (br ? (s_id - 160) : s_id) * EPB;
    const int4* rows4 = (const int4*)(rows + ebase);
    const int4* cols4 = (const int4*)(cols + ebase);

    // pass 1: count
    #pragma unroll
    for (int j = 0; j < 8; ++j) {
      int4 rv = rows4[j * 256 + t];
      atomicAdd(&hcnt[(br << 9) | (rv.x >> 7)], 1);
      atomicAdd(&hcnt[(br << 9) | (rv.y >> 7)], 1);
      atomicAdd(&hcnt[(br << 9) | (rv.z >> 7)], 1);
      atomicAdd(&hcnt[(br << 9) | (rv.w >> 7)], 1);
    }
    __syncthreads();

    // claim global ranges: one atomic per nonzero (block,bin)
    #pragma unroll
    for (int k = 0; k < 4; ++k) {
      int bin = k * 256 + t;
      int cnt = hcnt[bin];
      if (cnt > 0) hbase[bin] = atomicAdd(&bucket_cnt[bin], cnt);
    }
    __syncthreads();

    // pass 2: re-read, re-rank, scatter in contiguous per-bin chunks
    #pragma unroll
    for (int j = 0; j < 8; ++j) {
      int4 rv = rows4[j * 256 + t];
      int4 cv = cols4[j * 256 + t];
      int rr[4] = {rv.x, rv.y, rv.z, rv.w};
      int cc4[4] = {cv.x, cv.y, cv.z, cv.w};
      #pragma unroll
      for (int e = 0; e < 4; ++e) {
        int bin = (br << 9) | (rr[e] >> 7);
        int rank = atomicAdd(&rnk[bin], 1);
        int pos = hbase[bin] + rank;
        if (pos < BCAP)
          bpack[(bin << 12) + pos] =
              ((unsigned)cc4[e] << 7) | (unsigned)(rr[e] & 127);
      }
    }
    return;
  }

  // ---- hproj role ----
  int nbuck_before = (q + 1 < BK_B) ? (q + 1) : BK_B;
  int h_id = b - nbuck_before;

  int* suid = (int*)smem;                              // [BM]
  unsigned short* sx = (unsigned short*)(smem + 512);  // [BM*XS2]

  int nbase = h_id * BM;
  if (t < BM) suid[t] = (nbase + t < M_N) ? uids[nbase + t] : 0;
  __syncthreads();

  int chunk = t & 15, rb = t >> 4;
  #pragma unroll
  for (int i = 0; i < BM / 16; ++i) {
    int row = i * 16 + rb;
    float4 v = ((const float4*)emb)[(size_t)suid[row] * 16 + chunk];
    uint2 p;
    p.x = pk2(v.x, v.y);
    p.y = pk2(v.z, v.w);
    *(uint2*)&sx[row * XS2 + chunk * 4] = p;
  }
  __syncthreads();

  int l = t & 63, w = t >> 6;
  bf16x8 bf[NFRAG];
  #pragma unroll
  for (int qq = 0; qq < NFRAG; ++qq)
    bf[qq] = *(const bf16x8*)&frag_buf[(qq * 64 + l) * 4];

  f32x4 acc[2][NCT];
  #pragma unroll
  for (int rt = 0; rt < 2; ++rt)
    #pragma unroll
    for (int ct = 0; ct < NCT; ++ct)
      acc[rt][ct] = (f32x4){0.f, 0.f, 0.f, 0.f};

  int wr0 = w * 32;
  #pragma unroll
  for (int rt = 0; rt < 2; ++rt) {
    const unsigned short* arow =
        &sx[(wr0 + rt * 16 + (l & 15)) * XS2 + (l >> 4) * 8];
    bf16x8 a0 = *(const bf16x8*)(arow);
    bf16x8 a1 = *(const bf16x8*)(arow + 32);
    #pragma unroll
    for (int ct = 0; ct < NCT; ++ct) {
      acc[rt][ct] = __builtin_amdgcn_mfma_f32_16x16x32_bf16(
          a0, bf[2 * ct + 0], acc[rt][ct], 0, 0, 0);
      acc[rt][ct] = __builtin_amdgcn_mfma_f32_16x16x32_bf16(
          a1, bf[2 * ct + 1], acc[rt][ct], 0, 0, 0);
    }
  }

  __syncthreads();
  unsigned short* sb = sx;
  unsigned short* su = sx + BM * 32;

  int g = l >> 4, cc = l & 15;
  #pragma unroll
  for (int rt = 0; rt < 2; ++rt) {
    int rl0 = wr0 + rt * 16 + g * 4;
    #pragma unroll
    for (int r = 0; r < 4; ++r) {
      int rl = rl0 + r;
      #pragma unroll
      for (int ct = 0; ct < 4; ++ct) {
        unsigned short hv = f2bf(acc[rt][ct][r]);
        if (ct < 2) sb[rl * 32 + ct * 16 + cc] = hv;
        else su[rl * 32 + (ct - 2) * 16 + cc] = hv;
      }
      int row = nbase + rl;
      if (row < M_N) {
        float dv = acc[rt][4][r];
        if (cc == 1) adb[row] = dv;
        else if (cc == 3) adu[row] = dv;
        else if (cc == 0) { if (row < B_N) asb[row] = dv; }
        else if (cc == 2) { if (row < B_N) asu[row] = dv; }
      }
    }
  }
  __syncthreads();

  const uint4* sb4 = (const uint4*)sb;
  const uint4* su4 = (const uint4*)su;
  uint4* hb4 = (uint4*)(hb + (size_t)nbase * 32);
  uint4* hu4 = (uint4*)(hu + (size_t)nbase * 32);
  int maxq = (M_N - nbase) * 4;
  #pragma unroll
  for (int k = 0; k < 2; ++k) {
    int idx = t + k * 256;
    if (idx < maxq) {
      hb4[idx] = sb4[idx];
      hu4[idx] = su4[idx];
    }
  }
}

// Per-bucket aggregation (unchanged): in-LDS counting sort by row, then
// register accumulation; no LDS atomics in the hot loop.
__global__ __launch_bounds__(512) void k_agg2(
    const int* __restrict__ bucket_cnt, const unsigned* __restrict__ bpack,
    const int* __restrict__ selfc,
    const unsigned short* __restrict__ hb, const unsigned short* __restrict__ hu,
    const float* __restrict__ adb, const float* __restrict__ asb,
    const float* __restrict__ adu, const float* __restrict__ asu,
    float* __restrict__ out)
{
  __shared__ float asv[128];
  __shared__ int hist[128];
  __shared__ int sc[128];
  __shared__ int scol[BCAP];
  __shared__ float sev[BCAP];

  int t = threadIdx.x;
  int b = blockIdx.x;
  int br = b >> 9;
  int rbase = (b & 511) << 7;

  const unsigned short* h = br ? hu : hb;
  const float* adst = br ? adu : adb;
  const float* asrc = br ? asu : asb;

  if (t < 128) {
    hist[t] = 0;
    asv[t] = asrc[rbase + t];
  }
  __syncthreads();

  int cnt = bucket_cnt[b];
  if (cnt > BCAP) cnt = BCAP;
  const unsigned* bp = bpack + ((size_t)b << 12);

  unsigned v8[8];
  float ev8[8];
  int rk8[8];
  #pragma unroll
  for (int j = 0; j < 8; ++j) {
    int i = j * 512 + t;
    bool ok = i < cnt;
    unsigned v = ok ? bp[i] : 0u;
    int c = v >> 7;
    int r7 = v & 127;
    float s = asv[r7] + adst[c];
    float scv = s > 0.f ? s : 0.2f * s;
    v8[j] = v;
    ev8[j] = __expf(-scv);
    rk8[j] = ok ? atomicAdd(&hist[r7], 1) : 0;
  }
  __syncthreads();

  if (t < 128) sc[t] = hist[t];
  __syncthreads();
  for (int off = 1; off < 128; off <<= 1) {
    int add = (t < 128 && t >= off) ? sc[t - off] : 0;
    __syncthreads();
    if (t < 128) sc[t] += add;
    __syncthreads();
  }

  #pragma unroll
  for (int j = 0; j < 8; ++j) {
    int i = j * 512 + t;
    if (i < cnt) {
      unsigned v = v8[j];
      int r7 = v & 127;
      int pos = sc[r7] - hist[r7] + rk8[j];
      scol[pos] = v >> 7;
      sev[pos] = ev8[j];
    }
  }
  __syncthreads();

  int gid = t >> 5, lane = t & 31;
  for (int rr8 = 0; rr8 < 8; ++rr8) {
    int rr = gid * 8 + rr8;
    int r = rbase + rr;
    int s0 = sc[rr] - hist[rr];
    int n = hist[rr];

    int c0 = selfc[r];
    float sse = asv[rr] + adst[c0];
    float ssc = sse > 0.f ? sse : 0.2f * sse;
    float ev0 = __expf(-ssc);
    float acc = ev0 * bf2f(h[(size_t)c0 * 32 + lane]);
    float den = ev0;

    for (int j0 = 0; j0 < n; j0 += 8) {
      int c8[8];
      float e8[8];
      float hv8[8];
      #pragma unroll
      for (int qq = 0; qq < 8; ++qq) {
        int j = j0 + qq;
        int jj = (j < n) ? j : j0;
        c8[qq] = scol[s0 + jj];
        e8[qq] = (j < n) ? sev[s0 + jj] : 0.f;
      }
      #pragma unroll
      for (int qq = 0; qq < 8; ++qq)
        hv8[qq] = bf2f(h[(size_t)c8[qq] * 32 + lane]);
      #pragma unroll
      for (int qq = 0; qq < 8; ++qq) {
        acc = fmaf(e8[qq], hv8[qq], acc);
        den += e8[qq];
      }
    }

    float x = acc / den;
    out[(((size_t)br * B_N + r) << 5) + lane] =
        (x > 0.f) ? x : (__expf(x) - 1.f);
  }
}

extern "C" void kernel_launch(void* const* d_in, const int* in_sizes, int n_in,
                              void* d_out, int out_size, void* d_ws, size_t ws_size,
                              hipStream_t stream) {
  const float* emb = (const float*)d_in[0];
  const float* Wb  = (const float*)d_in[1];
  const float* ab  = (const float*)d_in[2];
  const float* Wu  = (const float*)d_in[3];
  const float* au  = (const float*)d_in[4];
  const int* uids  = (const int*)d_in[5];
  const int* selfc = (const int*)d_in[6];
  const int* prow  = (const int*)d_in[7];
  const int* pcol  = (const int*)d_in[8];
  const int* nrow  = (const int*)d_in[9];
  const int* ncol  = (const int*)d_in[10];
  float* out = (float*)d_out;

  char* ws = (char*)d_ws;
  size_t off = 0;
  auto alloc = [&](size_t bytes) -> void* {
    void* p = ws + off;
    off += (bytes + 255) & ~(size_t)255;
    return p;
  };
  unsigned short* hb = (unsigned short*)alloc((size_t)M_N * OUT_D * 2);
  unsigned short* hu = (unsigned short*)alloc((size_t)M_N * OUT_D * 2);
  float* adb = (float*)alloc((size_t)M_N * 4);
  float* adu = (float*)alloc((size_t)M_N * 4);
  float* asb = (float*)alloc((size_t)B_N * 4);
  float* asu = (float*)alloc((size_t)B_N * 4);
  unsigned* frag_buf = (unsigned*)alloc((size_t)NFRAG * 64 * 4 * 4);
  int* bucket_cnt = (int*)alloc((size_t)NBUCK * 4);
  unsigned* bpack = (unsigned*)alloc((size_t)NBUCK * BCAP * 4);

  k_init<<<2, 256, 0, stream>>>(bucket_cnt, Wb, ab, Wu, au, frag_buf);

  k_mid<<<BK_B + HP_B, 256, 0, stream>>>(emb, uids, frag_buf,
                                         hb, hu, adb, adu, asb, asu,
                                         prow, pcol, nrow, ncol,
                                         bucket_cnt, bpack);

  k_agg2<<<NBUCK, 512, 0, stream>>>(bucket_cnt, bpack, selfc,
                                    hb, hu, adb, asb, adu, asu, out);
}

// Round 17
// 183.432 us; speedup vs baseline: 1.1375x; 1.1375x over previous
//
#include <hip/hip_runtime.h>

#define B_N 65536
#define M_N 1000000
#define E_N 1310720
#define IN_D 64
#define OUT_D 32
#define BM 128   // rows per block in k_hproj
#define XS2 72   // sx row stride in SHORTS (144 B, 16B-aligned rows)
#define NCT 5    // col-tiles: 4 x 16 h-cols + 1 tile holding folded a-dot cols
#define NFRAG (NCT * 2)
#define NBUCK 1024        // (branch<<9) | (row>>7)
#define BCAP 4096         // per-bucket capacity (mean 2560, max ~2800)
#define BK_B 320          // bucket blocks: 320 x 8192 edges = 2*E_N exactly

typedef __attribute__((ext_vector_type(8))) short bf16x8;
typedef __attribute__((ext_vector_type(4))) float f32x4;

__device__ __forceinline__ unsigned short f2bf(float f) {
  unsigned u = __float_as_uint(f);
  u += 0x7fffu + ((u >> 16) & 1u);
  return (unsigned short)(u >> 16);
}
__device__ __forceinline__ unsigned pk2(float a, float b) {
  return (unsigned)f2bf(a) | ((unsigned)f2bf(b) << 16);
}
__device__ __forceinline__ float bf2f(unsigned short s) {
  return __uint_as_float(((unsigned)s) << 16);
}

// block 0: zero bucket_cnt; block 1: pack B_ext MFMA fragments.
__global__ __launch_bounds__(256) void k_init(
    int* __restrict__ bucket_cnt,
    const float* __restrict__ Wb, const float* __restrict__ ab,
    const float* __restrict__ Wu, const float* __restrict__ au,
    unsigned* __restrict__ frag_buf)
{
  int t = threadIdx.x;
  if (blockIdx.x == 0) {
    ((int4*)bucket_cnt)[t] = (int4){0, 0, 0, 0};  // 1024 ints = 256 int4
    return;
  }
  for (int p = t; p < NFRAG * 64 * 4; p += 256) {
    int q = p >> 8;
    int rem = p & 255;
    int l = rem >> 2;
    int d = rem & 3;
    int ct = q >> 1, S = q & 1;
    int kb = 32 * S + 8 * (l >> 4);
    int n = 16 * ct + (l & 15);
    float v[2];
    #pragma unroll
    for (int e = 0; e < 2; ++e) {
      int kk = kb + 2 * d + e;
      float val;
      if (n < 32) val = Wb[kk * 32 + n];
      else if (n < 64) val = Wu[kk * 32 + (n - 32)];
      else if (n < 68) {
        const float* W = (n < 66) ? Wb : Wu;
        const float* av = (n < 66) ? ab : au;
        int hi = (n & 1) ? 32 : 0;
        float acc = 0.f;
        for (int j = 0; j < 32; ++j) acc = fmaf(W[kk * 32 + j], av[hi + j], acc);
        val = acc;
      } else val = 0.f;
      v[e] = val;
    }
    frag_buf[p] = pk2(v[0], v[1]);
  }
}

// Coarse bucket sort: 8192 edges/block over 320 blocks (1.25 blocks/CU).
// LDS hist -> ONE global atomic per (block,bin) -> packed chunk writes.
__global__ __launch_bounds__(1024) void k_bucket(
    const int* __restrict__ prow, const int* __restrict__ pcol,
    const int* __restrict__ nrow, const int* __restrict__ ncol,
    int* __restrict__ bucket_cnt, unsigned* __restrict__ bpack)
{
  __shared__ int hcnt[NBUCK];
  __shared__ int hbase[NBUCK];
  int t = threadIdx.x;
  int b = blockIdx.x;
  hcnt[t] = 0;
  __syncthreads();

  int br = (b >= 160) ? 1 : 0;
  const int* rows = br ? nrow : prow;
  const int* cols = br ? ncol : pcol;
  int ebase = (br ? (b - 160) : b) * 8192;

  int bins[8];
  int ranks[8];
  unsigned vals[8];
  #pragma unroll
  for (int j = 0; j < 8; ++j) {
    int i = ebase + j * 1024 + t;
    int r = rows[i];
    int c = cols[i];
    int bin = (br << 9) | (r >> 7);
    bins[j] = bin;
    vals[j] = ((unsigned)c << 7) | (unsigned)(r & 127);
    ranks[j] = atomicAdd(&hcnt[bin], 1);
  }
  __syncthreads();

  int cnt = hcnt[t];
  if (cnt > 0) hbase[t] = atomicAdd(&bucket_cnt[t], cnt);
  __syncthreads();

  #pragma unroll
  for (int j = 0; j < 8; ++j) {
    int bin = bins[j];
    int lpos = hbase[bin] + ranks[j];
    if (lpos < BCAP) bpack[(bin << 12) + lpos] = vals[j];
  }
}

// MFMA h-projection, BM=128 rows/block; LDS-repack epilogue (unchanged).
__global__ __launch_bounds__(256) void k_hproj(
    const float* __restrict__ emb, const int* __restrict__ uids,
    const unsigned* __restrict__ frag_buf,
    unsigned short* __restrict__ hb, unsigned short* __restrict__ hu,
    float* __restrict__ adb, float* __restrict__ adu,
    float* __restrict__ asb, float* __restrict__ asu)
{
  __shared__ int suid[BM];
  __shared__ unsigned short sx[BM * XS2];
  int t = threadIdx.x;
  int nbase = blockIdx.x * BM;
  if (t < BM) suid[t] = (nbase + t < M_N) ? uids[nbase + t] : 0;
  __syncthreads();

  int chunk = t & 15, rb = t >> 4;
  #pragma unroll
  for (int i = 0; i < BM / 16; ++i) {
    int row = i * 16 + rb;
    float4 v = ((const float4*)emb)[(size_t)suid[row] * 16 + chunk];
    uint2 p;
    p.x = pk2(v.x, v.y);
    p.y = pk2(v.z, v.w);
    *(uint2*)&sx[row * XS2 + chunk * 4] = p;
  }
  __syncthreads();

  int l = t & 63, w = t >> 6;
  bf16x8 bf[NFRAG];
  #pragma unroll
  for (int q = 0; q < NFRAG; ++q)
    bf[q] = *(const bf16x8*)&frag_buf[(q * 64 + l) * 4];

  f32x4 acc[2][NCT];
  #pragma unroll
  for (int rt = 0; rt < 2; ++rt)
    #pragma unroll
    for (int ct = 0; ct < NCT; ++ct)
      acc[rt][ct] = (f32x4){0.f, 0.f, 0.f, 0.f};

  int wr0 = w * 32;
  #pragma unroll
  for (int rt = 0; rt < 2; ++rt) {
    const unsigned short* arow =
        &sx[(wr0 + rt * 16 + (l & 15)) * XS2 + (l >> 4) * 8];
    bf16x8 a0 = *(const bf16x8*)(arow);
    bf16x8 a1 = *(const bf16x8*)(arow + 32);
    #pragma unroll
    for (int ct = 0; ct < NCT; ++ct) {
      acc[rt][ct] = __builtin_amdgcn_mfma_f32_16x16x32_bf16(
          a0, bf[2 * ct + 0], acc[rt][ct], 0, 0, 0);
      acc[rt][ct] = __builtin_amdgcn_mfma_f32_16x16x32_bf16(
          a1, bf[2 * ct + 1], acc[rt][ct], 0, 0, 0);
    }
  }

  __syncthreads();
  unsigned short* sb = sx;
  unsigned short* su = sx + BM * 32;

  int g = l >> 4, cc = l & 15;
  #pragma unroll
  for (int rt = 0; rt < 2; ++rt) {
    int rl0 = wr0 + rt * 16 + g * 4;
    #pragma unroll
    for (int r = 0; r < 4; ++r) {
      int rl = rl0 + r;
      #pragma unroll
      for (int ct = 0; ct < 4; ++ct) {
        unsigned short hv = f2bf(acc[rt][ct][r]);
        if (ct < 2) sb[rl * 32 + ct * 16 + cc] = hv;
        else su[rl * 32 + (ct - 2) * 16 + cc] = hv;
      }
      int row = nbase + rl;
      if (row < M_N) {
        float dv = acc[rt][4][r];
        if (cc == 1) adb[row] = dv;
        else if (cc == 3) adu[row] = dv;
        else if (cc == 0) { if (row < B_N) asb[row] = dv; }
        else if (cc == 2) { if (row < B_N) asu[row] = dv; }
      }
    }
  }
  __syncthreads();

  const uint4* sb4 = (const uint4*)sb;
  const uint4* su4 = (const uint4*)su;
  uint4* hb4 = (uint4*)(hb + (size_t)nbase * 32);
  uint4* hu4 = (uint4*)(hu + (size_t)nbase * 32);
  int maxq = (M_N - nbase) * 4;
  #pragma unroll
  for (int k = 0; k < 2; ++k) {
    int idx = t + k * 256;
    if (idx < maxq) {
      hb4[idx] = sb4[idx];
      hu4[idx] = su4[idx];
    }
  }
}

// Per-bucket aggregation (R13): in-LDS counting sort by row, then register
// accumulation; no LDS atomics in the hot loop.
__global__ __launch_bounds__(512) void k_agg2(
    const int* __restrict__ bucket_cnt, const unsigned* __restrict__ bpack,
    const int* __restrict__ selfc,
    const unsigned short* __restrict__ hb, const unsigned short* __restrict__ hu,
    const float* __restrict__ adb, const float* __restrict__ asb,
    const float* __restrict__ adu, const float* __restrict__ asu,
    float* __restrict__ out)
{
  __shared__ float asv[128];
  __shared__ int hist[128];
  __shared__ int sc[128];
  __shared__ int scol[BCAP];
  __shared__ float sev[BCAP];

  int t = threadIdx.x;
  int b = blockIdx.x;
  int br = b >> 9;
  int rbase = (b & 511) << 7;

  const unsigned short* h = br ? hu : hb;
  const float* adst = br ? adu : adb;
  const float* asrc = br ? asu : asb;

  if (t < 128) {
    hist[t] = 0;
    asv[t] = asrc[rbase + t];
  }
  __syncthreads();

  int cnt = bucket_cnt[b];
  if (cnt > BCAP) cnt = BCAP;
  const unsigned* bp = bpack + ((size_t)b << 12);

  unsigned v8[8];
  float ev8[8];
  int rk8[8];
  #pragma unroll
  for (int j = 0; j < 8; ++j) {
    int i = j * 512 + t;
    bool ok = i < cnt;
    unsigned v = ok ? bp[i] : 0u;
    int c = v >> 7;
    int r7 = v & 127;
    float s = asv[r7] + adst[c];
    float scv = s > 0.f ? s : 0.2f * s;
    v8[j] = v;
    ev8[j] = __expf(-scv);
    rk8[j] = ok ? atomicAdd(&hist[r7], 1) : 0;
  }
  __syncthreads();

  if (t < 128) sc[t] = hist[t];
  __syncthreads();
  for (int off = 1; off < 128; off <<= 1) {
    int add = (t < 128 && t >= off) ? sc[t - off] : 0;
    __syncthreads();
    if (t < 128) sc[t] += add;
    __syncthreads();
  }

  #pragma unroll
  for (int j = 0; j < 8; ++j) {
    int i = j * 512 + t;
    if (i < cnt) {
      unsigned v = v8[j];
      int r7 = v & 127;
      int pos = sc[r7] - hist[r7] + rk8[j];
      scol[pos] = v >> 7;
      sev[pos] = ev8[j];
    }
  }
  __syncthreads();

  int gid = t >> 5, lane = t & 31;
  for (int rr8 = 0; rr8 < 8; ++rr8) {
    int rr = gid * 8 + rr8;
    int r = rbase + rr;
    int s0 = sc[rr] - hist[rr];
    int n = hist[rr];

    int c0 = selfc[r];
    float sse = asv[rr] + adst[c0];
    float ssc = sse > 0.f ? sse : 0.2f * sse;
    float ev0 = __expf(-ssc);
    float acc = ev0 * bf2f(h[(size_t)c0 * 32 + lane]);
    float den = ev0;

    for (int j0 = 0; j0 < n; j0 += 8) {
      int c8[8];
      float e8[8];
      float hv8[8];
      #pragma unroll
      for (int q = 0; q < 8; ++q) {
        int j = j0 + q;
        int jj = (j < n) ? j : j0;
        c8[q] = scol[s0 + jj];
        e8[q] = (j < n) ? sev[s0 + jj] : 0.f;
      }
      #pragma unroll
      for (int q = 0; q < 8; ++q)
        hv8[q] = bf2f(h[(size_t)c8[q] * 32 + lane]);
      #pragma unroll
      for (int q = 0; q < 8; ++q) {
        acc = fmaf(e8[q], hv8[q], acc);
        den += e8[q];
      }
    }

    float x = acc / den;
    out[(((size_t)br * B_N + r) << 5) + lane] =
        (x > 0.f) ? x : (__expf(x) - 1.f);
  }
}

extern "C" void kernel_launch(void* const* d_in, const int* in_sizes, int n_in,
                              void* d_out, int out_size, void* d_ws, size_t ws_size,
                              hipStream_t stream) {
  const float* emb = (const float*)d_in[0];
  const float* Wb  = (const float*)d_in[1];
  const float* ab  = (const float*)d_in[2];
  const float* Wu  = (const float*)d_in[3];
  const float* au  = (const float*)d_in[4];
  const int* uids  = (const int*)d_in[5];
  const int* selfc = (const int*)d_in[6];
  const int* prow  = (const int*)d_in[7];
  const int* pcol  = (const int*)d_in[8];
  const int* nrow  = (const int*)d_in[9];
  const int* ncol  = (const int*)d_in[10];
  float* out = (float*)d_out;

  char* ws = (char*)d_ws;
  size_t off = 0;
  auto alloc = [&](size_t bytes) -> void* {
    void* p = ws + off;
    off += (bytes + 255) & ~(size_t)255;
    return p;
  };
  unsigned short* hb = (unsigned short*)alloc((size_t)M_N * OUT_D * 2);
  unsigned short* hu = (unsigned short*)alloc((size_t)M_N * OUT_D * 2);
  float* adb = (float*)alloc((size_t)M_N * 4);
  float* adu = (float*)alloc((size_t)M_N * 4);
  float* asb = (float*)alloc((size_t)B_N * 4);
  float* asu = (float*)alloc((size_t)B_N * 4);
  unsigned* frag_buf = (unsigned*)alloc((size_t)NFRAG * 64 * 4 * 4);
  int* bucket_cnt = (int*)alloc((size_t)NBUCK * 4);
  unsigned* bpack = (unsigned*)alloc((size_t)NBUCK * BCAP * 4);

  k_init<<<2, 256, 0, stream>>>(bucket_cnt, Wb, ab, Wu, au, frag_buf);

  k_bucket<<<BK_B, 1024, 0, stream>>>(prow, pcol, nrow, ncol,
                                      bucket_cnt, bpack);

  k_hproj<<<(M_N + BM - 1) / BM, 256, 0, stream>>>(emb, uids, frag_buf,
                                                   hb, hu, adb, adu, asb, asu);

  k_agg2<<<NBUCK, 512, 0, stream>>>(bucket_cnt, bpack, selfc,
                                    hb, hu, adb, asb, adu, asu, out);
}